// Round 7
// baseline (44.618 us; speedup 1.0000x reference)
//
#include <hip/hip_runtime.h>

#define IMG_W 1024
#define IMG_H 1024

typedef float f32x4 __attribute__((ext_vector_type(4)));

// One block (512 threads, 8 waves) per QUAD of horizontally-adjacent 128x128
// tiles. 512 blocks = 2 blocks/CU (16 waves/CU). 4-stage software pipeline
// with cross-scan prefetch: loads(i+1) are issued BEFORE store(i-1)/hist(i)/
// scan(i), so HBM latency drains under the compute+barrier phases.
__global__ __launch_bounds__(512, 4) void clahe_kernel(const float* __restrict__ img,
                                                       float* __restrict__ out) {
    const int quad = blockIdx.x;          // 0..511
    const int t0 = quad << 2;             // first tile of the quad
    const int b  = t0 >> 6;
    const int ty = (t0 >> 3) & 7;
    const int tx = t0 & 7;                // 0 or 4

    const size_t base0 = ((size_t)b * IMG_H + (size_t)ty * 128) * IMG_W + (size_t)tx * 128;

    const int t = threadIdx.x;            // 0..511
    const int w = t >> 6;                 // wave id 0..7

    __shared__ int   hist[8][256];        // 8 KB
    __shared__ float cdf[2][256];         // 2 KB ping-pong
    __shared__ float exw[4];
    __shared__ float wsum[4];

    int* hflat = &hist[0][0];
    hflat[t] = 0; hflat[t + 512] = 0; hflat[t + 1024] = 0; hflat[t + 1536] = 0;
    __syncthreads();

    // thread's element j of a tile: row = (t>>5) + 16*j, col = (t&31)*4
    const size_t toff = (size_t)(t >> 5) * IMG_W + ((t & 31) << 2);
    const float* __restrict__ p0 = img + base0 + toff;
    float* __restrict__ d0 = out + base0 + toff;

    unsigned int pk[2][8];                // ping-pong packed 255-indices
    f32x4 vA[8], vB[8];                   // ping-pong load buffers (named: rule #20)

    auto binpack = [&](const f32x4 vv, unsigned int* pkp) {
        atomicAdd(&hist[w][min(255, (int)(vv.x * 256.0f))], 1);
        atomicAdd(&hist[w][min(255, (int)(vv.y * 256.0f))], 1);
        atomicAdd(&hist[w][min(255, (int)(vv.z * 256.0f))], 1);
        atomicAdd(&hist[w][min(255, (int)(vv.w * 256.0f))], 1);
        *pkp = (unsigned int)min(255, (int)(vv.x * 255.0f))
             | ((unsigned int)min(255, (int)(vv.y * 255.0f)) << 8)
             | ((unsigned int)min(255, (int)(vv.z * 255.0f)) << 16)
             | ((unsigned int)min(255, (int)(vv.w * 255.0f)) << 24);
    };

    auto load_tile = [&](int i, f32x4* dstv) {
        const float* pi = p0 + (size_t)i * 128;
        #pragma unroll
        for (int j = 0; j < 8; ++j)
            dstv[j] = *reinterpret_cast<const f32x4*>(pi + (size_t)j * 16 * IMG_W);
    };

    auto store_tile = [&](int i) {
        float* di = d0 + (size_t)i * 128;
        const int s = i & 1;
        #pragma unroll
        for (int j = 0; j < 8; ++j) {
            const unsigned int u = pk[s][j];
            f32x4 o;
            o.x = cdf[s][u & 255u];
            o.y = cdf[s][(u >> 8) & 255u];
            o.z = cdf[s][(u >> 16) & 255u];
            o.w = cdf[s][u >> 24];
            __builtin_nontemporal_store(
                o, reinterpret_cast<f32x4*>(di + (size_t)j * 16 * IMG_W));
        }
    };

    // clip + scan -> cdf[s]; zeroes hist for the next tile. One internal barrier.
    auto scan_fn = [&](int s) {
        int h = 0;
        float x = 0.0f;
        if (t < 256) {
            h = hist[0][t] + hist[1][t] + hist[2][t] + hist[3][t]
              + hist[4][t] + hist[5][t] + hist[6][t] + hist[7][t];

            float ex = (float)max(h - 128, 0);
            #pragma unroll
            for (int off = 32; off > 0; off >>= 1) ex += __shfl_xor(ex, off);
            if ((t & 63) == 0) exw[w] = ex;

            x = fminf((float)h, 128.0f);
            #pragma unroll
            for (int off = 1; off < 64; off <<= 1) {
                const float y = __shfl_up(x, off);
                if ((t & 63) >= off) x += y;
            }
            if ((t & 63) == 63) wsum[w] = x;
        }
        __syncthreads();
        hflat[t] = 0; hflat[t + 512] = 0; hflat[t + 1024] = 0; hflat[t + 1536] = 0;
        if (t < 256) {
            const float excess = exw[0] + exw[1] + exw[2] + exw[3];
            float prefix = 0.0f;
            if (w > 0) prefix += wsum[0];
            if (w > 1) prefix += wsum[1];
            if (w > 2) prefix += wsum[2];
            const float summinh = wsum[0] + wsum[1] + wsum[2] + wsum[3];
            const float e256 = excess * (1.0f / 256.0f);
            const float total = summinh + excess;
            cdf[s][t] = (x + prefix + (float)(t + 1) * e256) / total;
        }
    };

    // ---- prologue: tile 0 loads into vA
    load_tile(0, vA);

    // ---- iter 0: prefetch tile1 -> vB; hist tile0 from vA; scan0
    load_tile(1, vB);
    #pragma unroll
    for (int j = 0; j < 8; ++j) binpack(vA[j], &pk[0][j]);
    __syncthreads();
    scan_fn(0);
    __syncthreads();

    // ---- iter 1: prefetch tile2 -> vA; store tile0; hist tile1 from vB; scan1
    load_tile(2, vA);
    store_tile(0);
    #pragma unroll
    for (int j = 0; j < 8; ++j) binpack(vB[j], &pk[1][j]);
    __syncthreads();
    scan_fn(1);
    __syncthreads();

    // ---- iter 2: prefetch tile3 -> vB; store tile1; hist tile2 from vA; scan0
    load_tile(3, vB);
    store_tile(1);
    #pragma unroll
    for (int j = 0; j < 8; ++j) binpack(vA[j], &pk[0][j]);
    __syncthreads();
    scan_fn(0);
    __syncthreads();

    // ---- iter 3: store tile2; hist tile3 from vB; scan1
    store_tile(2);
    #pragma unroll
    for (int j = 0; j < 8; ++j) binpack(vB[j], &pk[1][j]);
    __syncthreads();
    scan_fn(1);
    __syncthreads();

    // ---- epilogue: store tile 3
    store_tile(3);
}

extern "C" void kernel_launch(void* const* d_in, const int* in_sizes, int n_in,
                              void* d_out, int out_size, void* d_ws, size_t ws_size,
                              hipStream_t stream) {
    const float* img = (const float*)d_in[0];
    float* out = (float*)d_out;
    clahe_kernel<<<512, 512, 0, stream>>>(img, out);
}